// Round 4
// baseline (338.829 us; speedup 1.0000x reference)
//
#include <hip/hip_runtime.h>
#include <hip/hip_bf16.h>

#define B_  32
#define C_  128
#define T_  8192
#define K_  5
#define MC  256          // M*C = fc1 outputs
#define WPB 81920        // per-sample weight elements: 128*5*128
#define XT_ROWS 8208     // 4 zero pad + 8192 + 12 zero pad (mult of 16)

typedef short bf16x8 __attribute__((ext_vector_type(8)));
typedef float f32x4  __attribute__((ext_vector_type(4)));

static __device__ __forceinline__ unsigned short f2bf(float f) {
    unsigned int u = __float_as_uint(f);
    u += 0x7FFFu + ((u >> 16) & 1u);
    return (unsigned short)(u >> 16);
}

static __device__ __forceinline__ void gload_lds16(const void* g, void* l) {
    // 16B direct global->LDS; HW: per-lane global src, uniform LDS base + lane*16
    __builtin_amdgcn_global_load_lds(
        (const __attribute__((address_space(1))) unsigned int*)g,
        (__attribute__((address_space(3))) unsigned int*)l, 16, 0, 0);
}

// ============================== FAST PATH ==============================

__global__ __launch_bounds__(256) void zero_gap(float* __restrict__ gap) {
    gap[blockIdx.x * 256 + threadIdx.x] = 0.f;
}

// zero the 16 pad rows per sample (rows 0..3 and 8196..8207)
__global__ __launch_bounds__(256) void zero_pads(unsigned short* __restrict__ xT) {
    const int b = blockIdx.x;
    const int r = threadIdx.x >> 4, c = threadIdx.x & 15;
    const int R = (r < 4) ? r : (8196 + r - 4);
    bf16x8 z = {0, 0, 0, 0, 0, 0, 0, 0};
    *(bf16x8*)((char*)(xT + (size_t)b * (XT_ROWS * 128)) + (size_t)R * 256 + 16 * c) = z;
}

// transpose x -> bf16 [b][R=t+4][ci] with chunk XOR swizzle, + GAP partial sums.
// grid (T/64, B), 256 threads. Tile: 128 ci x 64 t.
__global__ __launch_bounds__(256) void tgap_kernel(const float* __restrict__ x,
                                                   unsigned short* __restrict__ xT,
                                                   float* __restrict__ gap) {
    const int t0 = blockIdx.x * 64;
    const int b  = blockIdx.y;
    const int tid = threadIdx.x;
    const int ci = tid >> 1;           // 0..127
    const int half = tid & 1;          // which 32-t sub-range

    __shared__ unsigned short lt[64 * 128];   // [t_local][ci] bf16, 16 KB

    const float* xr = x + ((size_t)b * C_ + ci) * T_ + t0 + half * 32;
    float s = 0.f;
#pragma unroll
    for (int j = 0; j < 8; ++j) {
        float4 v = reinterpret_cast<const float4*>(xr)[j];
        s += v.x + v.y + v.z + v.w;
        int tt = half * 32 + j * 4;
        lt[(tt + 0) * 128 + ci] = f2bf(v.x);
        lt[(tt + 1) * 128 + ci] = f2bf(v.y);
        lt[(tt + 2) * 128 + ci] = f2bf(v.z);
        lt[(tt + 3) * 128 + ci] = f2bf(v.w);
    }
    s += __shfl_down(s, 1);
    if (!half) atomicAdd(&gap[b * C_ + ci], s);
    __syncthreads();

    // write 1024 x 16B chunks, swizzled slot = c ^ (R & 15)
    char* xTb = (char*)(xT + (size_t)b * (XT_ROWS * 128));
#pragma unroll
    for (int qq = 0; qq < 4; ++qq) {
        int q = qq * 256 + tid;
        int r = q >> 4, c = q & 15;
        int R = t0 + 4 + r;
        bf16x8 v = *reinterpret_cast<const bf16x8*>(&lt[r * 128 + c * 8]);
        *reinterpret_cast<bf16x8*>(xTb + (size_t)R * 256 + 16 * (c ^ (R & 15))) = v;
    }
}

// dynamic conv, fast: stage swizzled bf16 tile via global_load_lds (linear copy).
// grid (T/128, B), 256 threads = 4 waves; LDS 136 rows x 256 B = 34816 B.
__global__ __launch_bounds__(256, 4) void conv_fast(const unsigned short* __restrict__ xT,
                                                    const unsigned short* __restrict__ W,
                                                    float* __restrict__ out) {
    const int t0 = blockIdx.x * 128;
    const int b  = blockIdx.y;
    const int tid = threadIdx.x;
    const int w = tid >> 6, l = tid & 63;

    __shared__ unsigned short xs[136 * 128];   // byte-copy of xT rows t0..t0+135

    const char* gbase = (const char*)(xT + (size_t)b * (XT_ROWS * 128))
                        + (size_t)t0 * 256 + l * 16;
    // 34 chunks of 1 KB; wave w takes j = w, w+4, ...
    for (int j = w; j < 34; j += 4)
        gload_lds16(gbase + j * 1024, (char*)xs + j * 1024);
    __syncthreads();   // compiler drains vmcnt before barrier

    const int wr = w >> 1, wc = w & 1;
    const int lr = l & 15, lh = l >> 4;

    f32x4 acc[4][4];
#pragma unroll
    for (int mt = 0; mt < 4; ++mt)
#pragma unroll
        for (int nt = 0; nt < 4; ++nt)
#pragma unroll
            for (int r = 0; r < 4; ++r) acc[mt][nt][r] = 0.f;

    const unsigned short* Wb = W + (size_t)b * WPB;

#pragma unroll
    for (int k = 0; k < K_; ++k) {
#pragma unroll
        for (int kc = 0; kc < 4; ++kc) {
            bf16x8 Af[4], Bf[4];
#pragma unroll
            for (int mt = 0; mt < 4; ++mt) {
                int co = wr * 64 + mt * 16 + lr;
                Af[mt] = *reinterpret_cast<const bf16x8*>(
                    Wb + co * 640 + k * 128 + kc * 32 + 8 * lh);
            }
#pragma unroll
            for (int nt = 0; nt < 4; ++nt) {
                int row = wc * 64 + nt * 16 + lr + k + 2;   // i = R - t0
                int c   = 4 * kc + lh;
                int cs  = c ^ (row & 15);                    // baked swizzle
                Bf[nt] = *reinterpret_cast<const bf16x8*>(
                    (const char*)xs + row * 256 + cs * 16);
            }
#pragma unroll
            for (int mt = 0; mt < 4; ++mt)
#pragma unroll
                for (int nt = 0; nt < 4; ++nt)
                    acc[mt][nt] = __builtin_amdgcn_mfma_f32_16x16x32_bf16(
                        Af[mt], Bf[nt], acc[mt][nt], 0, 0, 0);
        }
    }

    float* ob = out + (size_t)b * C_ * T_;
#pragma unroll
    for (int mt = 0; mt < 4; ++mt) {
#pragma unroll
        for (int nt = 0; nt < 4; ++nt) {
            int tcol = t0 + wc * 64 + nt * 16 + lr;
#pragma unroll
            for (int r = 0; r < 4; ++r) {
                int co = wr * 64 + mt * 16 + lh * 4 + r;
                ob[(size_t)co * T_ + tcol] = acc[mt][nt][r];
            }
        }
    }
}

// ============================ FALLBACK PATH ============================

__global__ __launch_bounds__(256) void gap_kernel(const float* __restrict__ x,
                                                  const int* __restrict__ len,
                                                  float* __restrict__ gap) {
    const int row = blockIdx.x;
    const float* xr = x + (size_t)row * T_;
    const int tid = threadIdx.x;
    float s = 0.f;
    const float4* xv = reinterpret_cast<const float4*>(xr);
#pragma unroll
    for (int i = 0; i < T_ / 4 / 256; ++i) {
        float4 v = xv[tid + i * 256];
        s += v.x + v.y + v.z + v.w;
    }
#pragma unroll
    for (int off = 32; off; off >>= 1) s += __shfl_down(s, off);
    __shared__ float red[4];
    if ((tid & 63) == 0) red[tid >> 6] = s;
    __syncthreads();
    if (tid == 0) {
        float tot = red[0] + red[1] + red[2] + red[3];
        gap[row] = tot / (float)len[row >> 7];
    }
}

__global__ __launch_bounds__(256) void conv_kernel(const float* __restrict__ x,
                                                   const unsigned short* __restrict__ W,
                                                   float* __restrict__ out) {
    const int t0 = blockIdx.x * 128;
    const int b  = blockIdx.y;
    const int tid = threadIdx.x;
    __shared__ unsigned short xs[136 * 136];
    const float* xb = x + (size_t)b * C_ * T_;
#pragma unroll
    for (int it = 0; it < 17; ++it) {
        int i  = tid + it * 256;
        int cg = i / 136;
        int tl = i - cg * 136;
        int t  = t0 - 4 + tl;
        float v0 = 0.f, v1 = 0.f, v2 = 0.f, v3 = 0.f;
        if (t >= 0 && t < T_) {
            const float* p = xb + (size_t)(4 * cg) * T_ + t;
            v0 = p[0]; v1 = p[T_]; v2 = p[2 * T_]; v3 = p[3 * T_];
        }
        ushort4 pk;
        pk.x = f2bf(v0); pk.y = f2bf(v1); pk.z = f2bf(v2); pk.w = f2bf(v3);
        *reinterpret_cast<ushort4*>(&xs[tl * 136 + 4 * cg]) = pk;
    }
    __syncthreads();
    const int w  = tid >> 6;
    const int l  = tid & 63;
    const int wr = w >> 1, wc = w & 1;
    const int lr = l & 15, lh = l >> 4;
    f32x4 acc[4][4];
#pragma unroll
    for (int mt = 0; mt < 4; ++mt)
#pragma unroll
        for (int nt = 0; nt < 4; ++nt)
#pragma unroll
            for (int r = 0; r < 4; ++r) acc[mt][nt][r] = 0.f;
    const unsigned short* Wb = W + (size_t)b * WPB;
#pragma unroll
    for (int k = 0; k < K_; ++k) {
#pragma unroll
        for (int kc = 0; kc < 4; ++kc) {
            bf16x8 Af[4], Bf[4];
#pragma unroll
            for (int mt = 0; mt < 4; ++mt) {
                int co = wr * 64 + mt * 16 + lr;
                Af[mt] = *reinterpret_cast<const bf16x8*>(
                    Wb + co * 640 + k * 128 + kc * 32 + 8 * lh);
            }
#pragma unroll
            for (int nt = 0; nt < 4; ++nt) {
                int row = wc * 64 + nt * 16 + lr + k + 2;
                Bf[nt] = *reinterpret_cast<const bf16x8*>(
                    &xs[row * 136 + kc * 32 + 8 * lh]);
            }
#pragma unroll
            for (int mt = 0; mt < 4; ++mt)
#pragma unroll
                for (int nt = 0; nt < 4; ++nt)
                    acc[mt][nt] = __builtin_amdgcn_mfma_f32_16x16x32_bf16(
                        Af[mt], Bf[nt], acc[mt][nt], 0, 0, 0);
        }
    }
    float* ob = out + (size_t)b * C_ * T_;
#pragma unroll
    for (int mt = 0; mt < 4; ++mt) {
#pragma unroll
        for (int nt = 0; nt < 4; ++nt) {
            int tcol = t0 + wc * 64 + nt * 16 + lr;
#pragma unroll
            for (int r = 0; r < 4; ++r) {
                int co = wr * 64 + mt * 16 + lh * 4 + r;
                ob[(size_t)co * T_ + tcol] = acc[mt][nt][r];
            }
        }
    }
}

// ============================ SHARED SMALL KERNELS ============================

// fc1 for fast path: divides gap sums by len here (gap buffer holds raw sums)
__global__ __launch_bounds__(256) void fc1_kernel(const float* __restrict__ gap,
                                                  const int* __restrict__ len,
                                                  const float* __restrict__ w1,
                                                  const float* __restrict__ b1,
                                                  float* __restrict__ h,
                                                  int divide) {
    const int b = blockIdx.x;
    const int o = threadIdx.x;
    __shared__ float g[C_];
    if (o < C_) {
        float v = gap[b * C_ + o];
        if (divide) v /= (float)len[b];
        g[o] = v;
    }
    __syncthreads();
    float acc = b1[o];
    const float* wr = w1 + o * C_;
#pragma unroll 8
    for (int c = 0; c < C_; ++c) acc += g[c] * wr[c];
    h[b * MC + o] = 1.f / (1.f + expf(-acc));
}

__global__ __launch_bounds__(256) void wgen_kernel(const float* __restrict__ h,
                                                   const float* __restrict__ w2,
                                                   unsigned short* __restrict__ W) {
    const int idx = blockIdx.x * 256 + threadIdx.x;
    const int ci = idx & 127;
    const int t1 = idx >> 7;
    const int k  = t1 % 5;
    const int t2 = t1 / 5;
    const int co = t2 & 127;
    const int b  = t2 >> 7;
    const float hv = h[b * MC + 2 * co + (ci >= 64)];
    const float wv = w2[co * 640 + ci * 5 + k];
    W[idx] = f2bf(hv * wv);
}

extern "C" void kernel_launch(void* const* d_in, const int* in_sizes, int n_in,
                              void* d_out, int out_size, void* d_ws, size_t ws_size,
                              hipStream_t stream) {
    const float* x   = (const float*)d_in[0];
    const int*   len = (const int*)d_in[1];
    const float* w1  = (const float*)d_in[2];
    const float* b1  = (const float*)d_in[3];
    const float* w2  = (const float*)d_in[4];
    float* out = (float*)d_out;

    char* ws = (char*)d_ws;
    float* gap = (float*)ws;                              // 16 KB
    float* h   = (float*)(ws + 16384);                    // 32 KB
    unsigned short* W = (unsigned short*)(ws + 65536);    // 5.24 MB
    unsigned short* xT = (unsigned short*)(ws + 65536 + (size_t)B_ * WPB * 2);
    const size_t need = 65536 + (size_t)B_ * WPB * 2
                      + (size_t)B_ * XT_ROWS * C_ * 2;    // ~72.6 MB

    if (ws_size >= need) {
        zero_gap<<<B_ * C_ / 256, 256, 0, stream>>>(gap);
        zero_pads<<<B_, 256, 0, stream>>>(xT);
        dim3 gt(T_ / 64, B_);
        tgap_kernel<<<gt, 256, 0, stream>>>(x, xT, gap);
        fc1_kernel<<<B_, 256, 0, stream>>>(gap, len, w1, b1, h, 1);
        wgen_kernel<<<(B_ * WPB) / 256, 256, 0, stream>>>(h, w2, W);
        dim3 g(T_ / 128, B_);
        conv_fast<<<g, 256, 0, stream>>>(xT, W, out);
    } else {
        gap_kernel<<<B_ * C_, 256, 0, stream>>>(x, len, gap);
        fc1_kernel<<<B_, 256, 0, stream>>>(gap, len, w1, b1, h, 0);
        wgen_kernel<<<(B_ * WPB) / 256, 256, 0, stream>>>(h, w2, W);
        dim3 g(T_ / 128, B_);
        conv_kernel<<<g, 256, 0, stream>>>(x, W, out);
    }
}